// Round 6
// baseline (144.789 us; speedup 1.0000x reference)
//
#include <hip/hip_runtime.h>

typedef _Float16 f16;
typedef f16 f16x8 __attribute__((ext_vector_type(8)));
typedef f16 f16x4 __attribute__((ext_vector_type(4)));
typedef float f32x4 __attribute__((ext_vector_type(4)));
typedef float f32x16 __attribute__((ext_vector_type(16)));
typedef unsigned uint4v __attribute__((ext_vector_type(4)));

#define GLL(g, l) __builtin_amdgcn_global_load_lds((const __attribute__((address_space(1))) void*)(g), (__attribute__((address_space(3))) void*)(l), 16, 0, 0)

// ---------------- fp32 -> fp16 convert (x, Wq, Wk, Wv, Wo) ----------------
__global__ __launch_bounds__(256) void cvt_all(
    const float* __restrict__ x, const float* __restrict__ wq, const float* __restrict__ wk,
    const float* __restrict__ wv, const float* __restrict__ wo,
    f16* __restrict__ xh, f16* __restrict__ wqh, f16* __restrict__ wkh,
    f16* __restrict__ wvh, f16* __restrict__ woh)
{
  int i = blockIdx.x * 256 + threadIdx.x;   // vec4 index, total 1835008
  const float4* src; f16x4* dst; int off;
  if (i < 1048576)      { src = (const float4*)x;  dst = (f16x4*)xh;  off = i; }
  else if (i < 1310720) { src = (const float4*)wq; dst = (f16x4*)wqh; off = i - 1048576; }
  else if (i < 1441792) { src = (const float4*)wk; dst = (f16x4*)wkh; off = i - 1310720; }
  else if (i < 1572864) { src = (const float4*)wv; dst = (f16x4*)wvh; off = i - 1441792; }
  else                  { src = (const float4*)wo; dst = (f16x4*)woh; off = i - 1572864; }
  float4 v = src[off];
  f16x4 hv; hv[0] = (f16)v.x; hv[1] = (f16)v.y; hv[2] = (f16)v.z; hv[3] = (f16)v.w;
  dst[off] = hv;
}

// ---------------- GEMM: C = A(MxK) * B(NxK)^T, K=1024, tile 128x128, BK=32 ----------------
// MODE 0: Q/K projection. N = 1536 (Q 0..1023, K 1024..1535).
//         Q written head-major f16 PRE-SCALED by log2(e)/8; K head-major f16.
// MODE 1: out projection. N = 1024. Writes f32 + bias to Co.
template<int MODE>
__global__ __launch_bounds__(256) void gemm_k(
    const f16* __restrict__ A, const f16* __restrict__ B0, const f16* __restrict__ B1,
    f16* __restrict__ Qb, f16* __restrict__ Kb,
    const float* __restrict__ bo, float* __restrict__ Co)
{
  __shared__ __align__(16) f16 Ah[2][4096];
  __shared__ __align__(16) f16 Bh[2][4096];
  const int tid = threadIdx.x;
  const int bm = blockIdx.x & 31, bn = blockIdx.x >> 5;
  const f16* Bp;
  if (MODE == 0) {
    if (bn < 8)  Bp = B0 + (size_t)bn * 131072;
    else         Bp = B1 + (size_t)(bn - 8) * 131072;
  } else {
    Bp = B0 + (size_t)bn * 131072;
  }
  const f16* Ap = A + (size_t)bm * 131072;

  const int w = tid >> 6, lane = tid & 63, lr = lane & 15, lg = lane >> 4;
  const int wr = w >> 1, wc = w & 1;

  auto stage = [&](int b, int kt) {
#pragma unroll
    for (int i = 0; i < 2; ++i) {
      int o = tid * 16 + i * 4096;          // byte offset within the 8KB tile
      int row = o >> 6, colb = o & 63;
      GLL((const char*)Ap + (size_t)row * 2048 + kt * 64 + colb, (char*)&Ah[b][0] + o);
      GLL((const char*)Bp + (size_t)row * 2048 + kt * 64 + colb, (char*)&Bh[b][0] + o);
    }
  };

  f32x4 acc[4][4] = {};

  stage(0, 0);
  for (int kt = 0; kt < 32; ++kt) {
    const int cur = kt & 1;
    __syncthreads();
    if (kt < 31) stage(cur ^ 1, kt + 1);
    f16x8 af[4], bf[4];
#pragma unroll
    for (int mi = 0; mi < 4; ++mi)
      af[mi] = *(const f16x8*)((const char*)&Ah[cur][0] + (wr * 64 + mi * 16 + lr) * 64 + lg * 16);
#pragma unroll
    for (int ni = 0; ni < 4; ++ni)
      bf[ni] = *(const f16x8*)((const char*)&Bh[cur][0] + (wc * 64 + ni * 16 + lr) * 64 + lg * 16);
#pragma unroll
    for (int mi = 0; mi < 4; ++mi)
#pragma unroll
      for (int ni = 0; ni < 4; ++ni)
        acc[mi][ni] = __builtin_amdgcn_mfma_f32_16x16x32_f16(af[mi], bf[ni], acc[mi][ni], 0, 0, 0);
    __syncthreads();
  }

  const float C1 = 0.18033688011112042f;    // log2(e)/8 folded into Q
#pragma unroll
  for (int mi = 0; mi < 4; ++mi) {
#pragma unroll
    for (int ni = 0; ni < 4; ++ni) {
      const int ncol = bn * 128 + wc * 64 + ni * 16 + lr;
#pragma unroll
      for (int j = 0; j < 4; ++j) {
        const int m = bm * 128 + wr * 64 + mi * 16 + lg * 4 + j;
        const float v = acc[mi][ni][j];
        if (MODE == 0) {
          const int nb = m >> 11, s = m & 2047;
          if (ncol < 1024) {
            const int hh = ncol >> 6, d = ncol & 63;
            Qb[(((size_t)(nb * 16 + hh)) * 2048 + s) * 64 + d] = (f16)(v * C1);
          } else {
            const int kh = (ncol - 1024) >> 6, d = ncol & 63;
            Kb[(((size_t)(nb * 8 + kh)) * 2048 + s) * 64 + d] = (f16)v;
          }
        } else {
          Co[(size_t)m * 1024 + ncol] = v + bo[ncol];
        }
      }
    }
  }
}

// ---------------- VT GEMM: VT = Wv * x^T, M=512, N=4096, tile 64x128 ----------------
// Output row-major [512][4096]: row m = kvh*64+d, col = n*2048+s -> coalesced stores,
// and exactly the [d][token] layout attn wants for V^T.
__global__ __launch_bounds__(256) void gemm_vt(
    const f16* __restrict__ A,   // wvh [512][1024]
    const f16* __restrict__ B,   // xh  [4096][1024]
    f16* __restrict__ C)         // VT  [512][4096]
{
  __shared__ __align__(16) f16 Ah[2][2048];
  __shared__ __align__(16) f16 Bh[2][4096];
  const int tid = threadIdx.x;
  const int bm = blockIdx.x & 7, bn = blockIdx.x >> 3;
  const f16* Ap = A + (size_t)bm * 65536;
  const f16* Bp = B + (size_t)bn * 131072;
  const int w = tid >> 6, lane = tid & 63, lr = lane & 15, lg = lane >> 4;
  const int wr = w >> 1, wc = w & 1;

  auto stage = [&](int b, int kt) {
    {
      int o = tid * 16;                     // A tile: 64 rows x 64B = 4KB
      int row = o >> 6, colb = o & 63;
      GLL((const char*)Ap + (size_t)row * 2048 + kt * 64 + colb, (char*)&Ah[b][0] + o);
    }
#pragma unroll
    for (int i = 0; i < 2; ++i) {
      int o = tid * 16 + i * 4096;          // B tile: 128 rows x 64B = 8KB
      int row = o >> 6, colb = o & 63;
      GLL((const char*)Bp + (size_t)row * 2048 + kt * 64 + colb, (char*)&Bh[b][0] + o);
    }
  };

  f32x4 acc[2][4] = {};
  stage(0, 0);
  for (int kt = 0; kt < 32; ++kt) {
    const int cur = kt & 1;
    __syncthreads();
    if (kt < 31) stage(cur ^ 1, kt + 1);
    f16x8 af[2], bf[4];
#pragma unroll
    for (int mi = 0; mi < 2; ++mi)
      af[mi] = *(const f16x8*)((const char*)&Ah[cur][0] + (wr * 32 + mi * 16 + lr) * 64 + lg * 16);
#pragma unroll
    for (int ni = 0; ni < 4; ++ni)
      bf[ni] = *(const f16x8*)((const char*)&Bh[cur][0] + (wc * 64 + ni * 16 + lr) * 64 + lg * 16);
#pragma unroll
    for (int mi = 0; mi < 2; ++mi)
#pragma unroll
      for (int ni = 0; ni < 4; ++ni)
        acc[mi][ni] = __builtin_amdgcn_mfma_f32_16x16x32_f16(af[mi], bf[ni], acc[mi][ni], 0, 0, 0);
    __syncthreads();
  }

#pragma unroll
  for (int mi = 0; mi < 2; ++mi)
#pragma unroll
    for (int ni = 0; ni < 4; ++ni) {
      const int ncol = bn * 128 + wc * 64 + ni * 16 + lr;
#pragma unroll
      for (int j = 0; j < 4; ++j) {
        const int m = bm * 64 + wr * 32 + mi * 16 + lg * 4 + j;
        C[(size_t)m * 4096 + ncol] = (f16)acc[mi][ni][j];
      }
    }
}

// ---------------- flash attention, swapped-operand 32x32, KV-split x2 ----------------
// 8 waves: waves 0-3 (half 0) do KV tiles 0..15, waves 4-7 (half 1) do 16..31.
// Defer-max online softmax (rescale only when tile max drifts >8 above running
// max: P <= 2^8, f16-safe). Row-sum l via MFMA ones-trick (A=1 -> every C row
// is the column sum, lane-local). Flash-combine of halves in LDS epilogue.
__global__ __launch_bounds__(512, 2) void attn_k(
    const f16* __restrict__ Qb, const f16* __restrict__ Kb, const f16* __restrict__ VTb,
    f16* __restrict__ Ob)
{
  __shared__ __align__(16) char SMEM[65536];

  const int tid = threadIdx.x, w = tid >> 6, l = tid & 63;
  const int lq = l & 31, hi = l >> 5;
  const int half = w >> 2, g = w & 3;
  const int qt = blockIdx.x, nh = blockIdx.y;
  const int n = nh >> 4, h = nh & 15, kvh = h >> 1;
  const int qb = qt * 128;
  const int qhat = qb + g * 32 + lq;

  // Q fragments (pre-scaled by log2e/8 in the projection epilogue)
  const f16* Qp = Qb + ((size_t)(n * 16 + h) * 2048 + qhat) * 64;
  f16x8 qf[4];
#pragma unroll
  for (int cd = 0; cd < 4; ++cd)
    qf[cd] = *(const f16x8*)(Qp + cd * 16 + hi * 8);

  const char* Kg = (const char*)(Kb + (size_t)(n * 8 + kvh) * 2048 * 64);      // [2048][64] f16
  const char* Vg = (const char*)(VTb + (size_t)kvh * 64 * 4096 + (size_t)n * 2048); // rows stride 8192B

  // staging by each half's 256 threads: linear LDS dest + XOR-swizzled source
  const int t256 = tid & 255;
  const int s0 = t256 * 16, s1 = s0 + 4096;
  const int r0 = s0 >> 7, c0 = ((s0 >> 4) & 7) ^ (r0 & 7);
  const int r1 = s1 >> 7, c1 = ((s1 >> 4) & 7) ^ (r1 & 7);
  char* KB0 = SMEM + half * 32768;   // per half: buf0 K@0 V@8192, buf1 K@16384 V@24576

  auto stageK = [&](int buf, int tb) {
    char* d = KB0 + buf * 16384;
    GLL(Kg + (size_t)(tb * 64 + r0) * 128 + c0 * 16, d + s0);
    GLL(Kg + (size_t)(tb * 64 + r1) * 128 + c1 * 16, d + s1);
  };
  auto stageV = [&](int buf, int tb) {
    char* d = KB0 + buf * 16384 + 8192;
    GLL(Vg + (size_t)r0 * 8192 + tb * 128 + c0 * 16, d + s0);
    GLL(Vg + (size_t)r1 * 8192 + tb * 128 + c1 * 16, d + s1);
  };

  f32x16 oacc[2] = {};
  f32x16 lacc = {};
  float p[2][16];
  float m_r = -1e30f;
  const float C1 = 0.18033688011112042f;           // log2(e)/8
  const float slt = exp2f(-(float)(h + 1)) * C1;   // alibi slope in exp2 domain
  const float qpos = (float)qhat;

  f16x8 ones;
#pragma unroll
  for (int i = 0; i < 8; ++i) ones[i] = (f16)1.0f;

  stageK(0, half * 16); stageV(0, half * 16);

  for (int t = 0; t < 16; ++t) {
    const int cur = t & 1;
    const int tb = half * 16 + t;
    __syncthreads();                       // compiler drains vmcnt before s_barrier
    if (t < 15) { stageK(cur ^ 1, tb + 1); stageV(cur ^ 1, tb + 1); }
    const char* Kl = KB0 + cur * 16384;
    const char* Vl = Kl + 8192;

    // ---- S^T = K * Q^T : lane owns column q=lq; scores in exp2 domain ----
#pragma unroll
    for (int kt = 0; kt < 2; ++kt) {
      f32x16 c = {};
#pragma unroll
      for (int cd = 0; cd < 4; ++cd) {
        const int row = kt * 32 + lq;
        f16x8 kf = *(const f16x8*)(Kl + row * 128 + (((2 * cd + hi) ^ (row & 7)) * 16));
        c = __builtin_amdgcn_mfma_f32_32x32x16_f16(kf, qf[cd], c, 0, 0, 0);
      }
      const float kb0 = (float)(tb * 64 + kt * 32 + 4 * hi);
#pragma unroll
      for (int r = 0; r < 16; ++r) {
        float kpos = kb0 + (float)((r & 3) + 8 * (r >> 2));
        p[kt][r] = fmaf(-fabsf(qpos - kpos), slt, c[r]);
      }
    }

    // ---- defer-max online softmax (P bounded by 2^8) ----
    float pmax = p[0][0];
#pragma unroll
    for (int kt = 0; kt < 2; ++kt)
#pragma unroll
      for (int r = 0; r < 16; ++r) pmax = fmaxf(pmax, p[kt][r]);
    pmax = fmaxf(pmax, __shfl_xor(pmax, 32));

    if (!__all(pmax - m_r <= 8.0f)) {
      float mn = fmaxf(m_r, pmax);
      float sc = __builtin_amdgcn_exp2f(m_r - mn);
      m_r = mn;
#pragma unroll
      for (int dt = 0; dt < 2; ++dt)
#pragma unroll
        for (int r = 0; r < 16; ++r) oacc[dt][r] *= sc;
#pragma unroll
      for (int r = 0; r < 16; ++r) lacc[r] *= sc;
    }
#pragma unroll
    for (int kt = 0; kt < 2; ++kt)
#pragma unroll
      for (int r = 0; r < 16; ++r)
        p[kt][r] = __builtin_amdgcn_exp2f(p[kt][r] - m_r);

    // ---- P^T B-fragments: cvt_pkrtz + permlane32_swap ----
    f16x8 pf[4];
#pragma unroll
    for (int c2 = 0; c2 < 4; ++c2) {
      const int T = c2 >> 1, e = c2 & 1;
      unsigned w0 = __builtin_bit_cast(unsigned, __builtin_amdgcn_cvt_pkrtz(p[T][8 * e + 0], p[T][8 * e + 1]));
      unsigned w2 = __builtin_bit_cast(unsigned, __builtin_amdgcn_cvt_pkrtz(p[T][8 * e + 4], p[T][8 * e + 5]));
      unsigned w1 = __builtin_bit_cast(unsigned, __builtin_amdgcn_cvt_pkrtz(p[T][8 * e + 2], p[T][8 * e + 3]));
      unsigned w3 = __builtin_bit_cast(unsigned, __builtin_amdgcn_cvt_pkrtz(p[T][8 * e + 6], p[T][8 * e + 7]));
      asm volatile("v_permlane32_swap_b32 %0, %1" : "+v"(w0), "+v"(w2));
      asm volatile("v_permlane32_swap_b32 %0, %1" : "+v"(w1), "+v"(w3));
      uint4v pu; pu.x = w0; pu.y = w1; pu.z = w2; pu.w = w3;
      pf[c2] = __builtin_bit_cast(f16x8, pu);
    }

    // ---- O^T += V^T * P^T ;  l += 1^T * P^T (MFMA ones-trick) ----
#pragma unroll
    for (int dt = 0; dt < 2; ++dt) {
#pragma unroll
      for (int ck = 0; ck < 4; ++ck) {
        const int row = dt * 32 + lq;
        f16x8 vf = *(const f16x8*)(Vl + row * 128 + (((2 * ck + hi) ^ (row & 7)) * 16));
        oacc[dt] = __builtin_amdgcn_mfma_f32_32x32x16_f16(vf, pf[ck], oacc[dt], 0, 0, 0);
      }
    }
#pragma unroll
    for (int ck = 0; ck < 4; ++ck)
      lacc = __builtin_amdgcn_mfma_f32_32x32x16_f16(ones, pf[ck], lacc, 0, 0, 0);
  }

  const float l_r = lacc[0];               // every row of lacc equals the column sum

  // ---- flash-combine of halves (m,l merge) + transpose + store ----
  float* Xo = (float*)SMEM;                 // [4 g][32 q][66] f32 partial O^T
  float* Xm = (float*)(SMEM + 33792);       // [4 g][32 q]
  float* Xl = (float*)(SMEM + 34304);       // [4 g][32 q]
  f16* Ot = (f16*)SMEM;                     // later: [128 q][72] f16

  __syncthreads();
  if (half) {                               // half 1 publishes partials
#pragma unroll
    for (int dt = 0; dt < 2; ++dt)
#pragma unroll
      for (int r = 0; r < 16; ++r) {
        const int d = dt * 32 + (r & 3) + 8 * (r >> 2) + 4 * hi;
        Xo[(g * 32 + lq) * 66 + d] = oacc[dt][r];
      }
    if (!hi) { Xm[g * 32 + lq] = m_r; Xl[g * 32 + lq] = l_r; }
  }
  __syncthreads();
  float fin[2][16];
  if (!half) {                              // half 0 merges
    const float m1 = Xm[g * 32 + lq], l1 = Xl[g * 32 + lq];
    const float mm = fmaxf(m_r, m1);
    const float a0 = __builtin_amdgcn_exp2f(m_r - mm);
    const float a1 = __builtin_amdgcn_exp2f(m1 - mm);
    const float linv = 1.0f / (l_r * a0 + l1 * a1);
#pragma unroll
    for (int dt = 0; dt < 2; ++dt)
#pragma unroll
      for (int r = 0; r < 16; ++r) {
        const int d = dt * 32 + (r & 3) + 8 * (r >> 2) + 4 * hi;
        fin[dt][r] = (oacc[dt][r] * a0 + Xo[(g * 32 + lq) * 66 + d] * a1) * linv;
      }
  }
  __syncthreads();
  if (!half) {                              // write transposed f16 tile
#pragma unroll
    for (int dt = 0; dt < 2; ++dt)
#pragma unroll
      for (int r = 0; r < 16; ++r) {
        const int d = dt * 32 + (r & 3) + 8 * (r >> 2) + 4 * hi;
        Ot[(g * 32 + lq) * 72 + d] = (f16)fin[dt][r];
      }
  }
  __syncthreads();
  {                                         // coalesced store: all 512 threads
    const int q = tid >> 2, seg = tid & 3;
    const f16* src = &Ot[q * 72 + seg * 16];
    f16* dst = Ob + (size_t)(n * 2048 + qb + q) * 1024 + h * 64 + seg * 16;
    *(f16x8*)(dst) = *(const f16x8*)(src);
    *(f16x8*)(dst + 8) = *(const f16x8*)(src + 8);
  }
}

extern "C" void kernel_launch(void* const* d_in, const int* in_sizes, int n_in,
                              void* d_out, int out_size, void* d_ws, size_t ws_size,
                              hipStream_t stream) {
  const float* x  = (const float*)d_in[0];
  const float* Wq = (const float*)d_in[1];
  const float* Wk = (const float*)d_in[2];
  const float* Wv = (const float*)d_in[3];
  const float* Wo = (const float*)d_in[4];
  const float* bo = (const float*)d_in[5];

  char* ws = (char*)d_ws;
  f16* xh  = (f16*)(ws);
  f16* wqh = (f16*)(ws + 8388608);
  f16* wkh = (f16*)(ws + 10485760);
  f16* wvh = (f16*)(ws + 11534336);
  f16* woh = (f16*)(ws + 12582912);
  f16* Qb  = (f16*)(ws + 14680064);
  f16* Kb  = (f16*)(ws + 23068672);
  f16* VTb = (f16*)(ws + 27262976);
  f16* Ob  = (f16*)(ws + 31457280);

  cvt_all<<<7168, 256, 0, stream>>>(x, Wq, Wk, Wv, Wo, xh, wqh, wkh, wvh, woh);
  gemm_k<0><<<384, 256, 0, stream>>>(xh, wqh, wkh, Qb, Kb, nullptr, nullptr);
  gemm_vt<<<256, 256, 0, stream>>>(wvh, xh, VTb);
  attn_k<<<dim3(16, 32), 512, 0, stream>>>(Qb, Kb, VTb, Ob);
  gemm_k<1><<<256, 256, 0, stream>>>(Ob, woh, nullptr, nullptr, nullptr, bo, (float*)d_out);
}